// Round 15
// baseline (414.428 us; speedup 1.0000x reference)
//
#include <hip/hip_runtime.h>
#include <math.h>

// Problem constants
constexpr int kB    = 4;
constexpr int kNSEM = 12;
constexpr int kH    = 480;
constexpr int kW    = 640;
constexpr int kNPIX = kH * kW;           // 307200
constexpr int kNCH  = 16;                // rgb(3) + depth(1) + sem(12)
constexpr int kVR   = 100;
constexpr int kNZ   = 80;
constexpr int kZLO  = 13;                // agent window [13,25)
constexpr int kZHI  = 25;
constexpr int kNCELL  = kVR * kVR * kNZ; // 800000 floor-cells
constexpr int kNCHUNK = kNCELL / 256;    // 3125

// ---- ws layout ----
// Region A (zeroed by ONE memset, per-batch stride A_STRIDE):
//   CNT (800000 u32) | PART (3136 u32) | COL (14x10000 f32)
// Region B (entries, per-batch stride kNPIX*ESZ), starts at entOff.
constexpr size_t A_CNT    = 0;
constexpr size_t A_PART   = (size_t)kNCELL * 4;          // 3,200,000
constexpr size_t A_COL    = A_PART + 12544;              // 3,212,544
constexpr size_t A_STRIDE = A_COL + (size_t)14 * 10000 * 4;  // 3,772,544

// Block hipcc contraction of the weight product into the accumulate add
// (XLA's scatter adds are separately rounded).
__device__ __forceinline__ float nofuse_f(float x) {
    asm volatile("" : "+v"(x));
    return x;
}

// XLA-jit canonical geometry — FROZEN (bit-exact vs golden, R12-R14):
//   p0 = fma(tx, rcpF, 250) * 0.2f
//   p1 = d * 0.2f
//   p2 = fma(fma(tz, rcpF, 88), 0.2f, 8)
__device__ __forceinline__ void geom_f(int xi, int zi, float d, float rcpF,
                                       float& p0, float& p1, float& p2) {
    float tx  = ((float)xi - 319.5f) * d;
    float tz  = (239.5f - (float)zi) * d;
    float x_w = fmaf(tx, rcpF, 250.0f);
    float z_w = fmaf(tz, rcpF, 88.0f);
    p0 = x_w * 0.2f;
    p1 = d   * 0.2f;
    p2 = fmaf(z_w, 0.2f, 8.0f);
}

__device__ __forceinline__ bool cellmask(const float* __restrict__ ob, int pix,
                                         float rcpF, unsigned& cell, unsigned& mask,
                                         float& d, float& p0, float& p1, float& p2,
                                         bool want_mask) {
    int zi = pix / kW, xi = pix - zi * kW;
    d = ob[3 * kNPIX + pix];
    geom_f(xi, zi, d, rcpF, p0, p1, p2);
    int fx = (int)floorf(p0), fy = (int)floorf(p1), fz = (int)floorf(p2);
    if (fx < 0 || fx >= kVR || fy < 0 || fy >= kVR || fz < 0 || fz >= kNZ)
        return false;
    cell = ((unsigned)(fx * kVR + fy)) * (unsigned)kNZ + (unsigned)fz;
    mask = 0;
    if (want_mask) {
#pragma unroll
        for (int c = 0; c < kNSEM; ++c)
            if (ob[(4 + c) * kNPIX + pix] != 0.0f) mask |= (1u << c);
    }
    return true;
}

// K1: count pixels per floor cell.
__global__ __launch_bounds__(256) void build_kernel(
        const float* __restrict__ obs, char* __restrict__ ws,
        int b0, int nb, float rcpF) {
    int t = blockIdx.x * blockDim.x + threadIdx.x;
    if (t >= nb * kNPIX) return;
    int lb = t / kNPIX, pix = t - lb * kNPIX;
    const float* ob = obs + (size_t)(b0 + lb) * kNCH * kNPIX;
    unsigned cell, mask; float d, p0, p1, p2;
    if (cellmask(ob, pix, rcpF, cell, mask, d, p0, p1, p2, false))
        atomicAdd((unsigned*)(ws + (size_t)lb * A_STRIDE + A_CNT) + cell, 1u);
}

// K2a: per 256-cell chunk — in-place chunk-exclusive scan; chunk total -> part.
__global__ __launch_bounds__(256) void scan_block_kernel(char* __restrict__ ws) {
    int blk = blockIdx.x, t = threadIdx.x;
    int lb = blk / kNCHUNK, chunk = blk - lb * kNCHUNK;
    char* base = ws + (size_t)lb * A_STRIDE;
    unsigned* cnt  = (unsigned*)(base + A_CNT);
    unsigned* part = (unsigned*)(base + A_PART);
    int i = chunk * 256 + t;
    unsigned v = cnt[i];
    __shared__ unsigned s[256];
    s[t] = v; __syncthreads();
#pragma unroll
    for (int dd = 1; dd < 256; dd <<= 1) {
        unsigned x = (t >= dd) ? s[t - dd] : 0u;
        __syncthreads();
        s[t] += x;
        __syncthreads();
    }
    cnt[i] = s[t] - v;
    if (t == 255) part[chunk] = s[255];
}

// K2b: one block per batch — in-place exclusive scan of the 3125 partials.
__global__ __launch_bounds__(256) void scan_partials_kernel(char* __restrict__ ws) {
    int lb = blockIdx.x, t = threadIdx.x;
    unsigned* p = (unsigned*)(ws + (size_t)lb * A_STRIDE + A_PART);
    const int per = (kNCHUNK + 255) / 256;    // 13
    int lo = t * per, hi = lo + per; if (hi > kNCHUNK) hi = kNCHUNK;
    unsigned sum = 0;
    for (int i = lo; i < hi; ++i) sum += p[i];
    __shared__ unsigned s[256];
    s[t] = sum; __syncthreads();
    unsigned own = sum;
#pragma unroll
    for (int dd = 1; dd < 256; dd <<= 1) {
        unsigned x = (t >= dd) ? s[t - dd] : 0u;
        __syncthreads();
        s[t] += x;
        __syncthreads();
    }
    unsigned running = s[t] - own;
    for (int i = lo; i < hi; ++i) {
        unsigned tmp = p[i]; p[i] = running; running += tmp;
    }
}

// K2c: cnt[i] += chunk base -> global exclusive offsets (= scatter cursor).
__global__ __launch_bounds__(256) void scan_add_kernel(char* __restrict__ ws) {
    int blk = blockIdx.x, t = threadIdx.x;
    int lb = blk / kNCHUNK, chunk = blk - lb * kNCHUNK;
    char* base = ws + (size_t)lb * A_STRIDE;
    unsigned* cnt = (unsigned*)(base + A_CNT);
    const unsigned* part = (const unsigned*)(base + A_PART);
    cnt[chunk * 256 + t] += part[chunk];
}

// K3: scatter entries into buckets. After: cnt[c] == END of bucket c.
template <int ESZ>
__global__ __launch_bounds__(256) void scatter_kernel(
        const float* __restrict__ obs, char* __restrict__ ws,
        int b0, int nb, size_t entOff, float rcpF) {
    int t = blockIdx.x * blockDim.x + threadIdx.x;
    if (t >= nb * kNPIX) return;
    int lb = t / kNPIX, pix = t - lb * kNPIX;
    const float* ob = obs + (size_t)(b0 + lb) * kNCH * kNPIX;
    unsigned cell, mask; float d, p0, p1, p2;
    if (!cellmask(ob, pix, rcpF, cell, mask, d, p0, p1, p2, true)) return;
    unsigned slot = atomicAdd(
        (unsigned*)(ws + (size_t)lb * A_STRIDE + A_CNT) + cell, 1u);
    unsigned key = ((unsigned)pix << 12) | mask;
    char* entBase = ws + entOff + (size_t)lb * ((size_t)kNPIX * ESZ);
    if constexpr (ESZ == 16) {
        uint4 e; e.x = key; e.y = __float_as_uint(p0);
        e.z = __float_as_uint(p1); e.w = __float_as_uint(p2);
        ((uint4*)entBase)[slot] = e;
    } else if constexpr (ESZ == 8) {
        uint2 e; e.x = key; e.y = __float_as_uint(d);
        ((uint2*)entBase)[slot] = e;
    } else {
        ((unsigned*)entBase)[slot] = key;
    }
}

// K3s: per cell — insertion-sort its bucket ascending by key (= pix order).
template <int ESZ>
__global__ __launch_bounds__(256) void sort_kernel(
        char* __restrict__ ws, int nb, size_t entOff) {
    int t = blockIdx.x * blockDim.x + threadIdx.x;
    if (t >= nb * kNCELL) return;
    int lb = t / kNCELL, c = t - lb * kNCELL;
    const unsigned* cnt = (const unsigned*)(ws + (size_t)lb * A_STRIDE + A_CNT);
    int lo = (c == 0) ? 0 : (int)cnt[c - 1];
    int hi = (int)cnt[c];
    char* entBase = ws + entOff + (size_t)lb * ((size_t)kNPIX * ESZ);
    if constexpr (ESZ == 16) {
        uint4* ent = (uint4*)entBase;
        for (int i = lo + 1; i < hi; ++i) {
            uint4 v = ent[i]; int j = i - 1;
            while (j >= lo && ent[j].x > v.x) { ent[j + 1] = ent[j]; --j; }
            ent[j + 1] = v;
        }
    } else if constexpr (ESZ == 8) {
        uint2* ent = (uint2*)entBase;
        for (int i = lo + 1; i < hi; ++i) {
            uint2 v = ent[i]; int j = i - 1;
            while (j >= lo && ent[j].x > v.x) { ent[j + 1] = ent[j]; --j; }
            ent[j + 1] = v;
        }
    } else {
        unsigned* ent = (unsigned*)entBase;
        for (int i = lo + 1; i < hi; ++i) {
            unsigned v = ent[i]; int j = i - 1;
            while (j >= lo && ent[j] > v) { ent[j + 1] = ent[j]; --j; }
            ent[j + 1] = v;
        }
    }
}

// K4 (LDS-staged, ESZ=16): block = (x0, y0..y0+2, all z). Stages the 8
// needed cell-columns' contiguous entry ranges + bucket ends into LDS; the
// per-voxel scan order and arithmetic are bit-identical to the proven R14
// path (same p bits, same corner order, same sorted buckets). Uniform
// fallback to global reads if the block's ranges exceed CAP.
constexpr int kCAP = 2048;               // 32 KB of uint4 entries
__global__ __launch_bounds__(256) void gather_lds_kernel(
        char* __restrict__ ws, int nb, size_t entOff) {
    __shared__ uint4    sEnt[kCAP];
    __shared__ unsigned sEndsRel[8][80];
    __shared__ unsigned sCellcol[8], sLo[8], sLen[8], sColBase[8];
    __shared__ unsigned sTotal;

    const int per = 99 * 33;
    int bid = blockIdx.x;
    int lb = bid / per, r = bid - lb * per;
    int x0 = r / 33 + 1;
    int yt = r - (r / 33) * 33;
    int y0 = yt * 3 + 1;

    char* base = ws + (size_t)lb * A_STRIDE;
    const unsigned* cnt = (const unsigned*)(base + A_CNT);
    const uint4* entG = (const uint4*)(ws + entOff + (size_t)lb * ((size_t)kNPIX * 16));

    int t = threadIdx.x;
    if (t < 8) {
        int jx = t >> 2, jy = t & 3;
        int cx = x0 - 1 + jx, cy = y0 - 1 + jy;
        unsigned cc = ((unsigned)(cx * kVR + cy)) * (unsigned)kNZ;
        unsigned lo = (cc == 0u) ? 0u : cnt[cc - 1];
        unsigned hi = cnt[cc + (kNZ - 1)];
        sCellcol[t] = cc; sLo[t] = lo; sLen[t] = hi - lo;
    }
    __syncthreads();
    if (t == 0) {
        unsigned b = 0;
        for (int j = 0; j < 8; ++j) { sColBase[j] = b; b += sLen[j]; }
        sTotal = b;
    }
    __syncthreads();
    for (int i = t; i < 8 * kNZ; i += 256) {
        int j = i / kNZ, cz = i - j * kNZ;
        sEndsRel[j][cz] = cnt[sCellcol[j] + cz] - sLo[j];
    }
    unsigned total = sTotal;
    bool useLds = (total <= (unsigned)kCAP);
    if (useLds) {
        for (unsigned i = t; i < total; i += 256) {
            int j = 0;
            while (j < 7 && i >= sColBase[j + 1]) ++j;
            sEnt[i] = entG[sLo[j] + (i - sColBase[j])];
        }
    }
    __syncthreads();

    if (t >= 3 * 79) return;
    int yy = t / 79, zz = t - yy * 79;
    int x = x0, y = y0 + yy, z = zz + 1;

    bool win = (z >= kZLO) && (z < kZHI);
    float xf = (float)x, yf = (float)y, zf = (float)z;

    float s0 = 0.0f;
    float ssem[kNSEM];
#pragma unroll
    for (int c = 0; c < kNSEM; ++c) ssem[c] = 0.0f;

#pragma unroll
    for (int cc8 = 0; cc8 < 8; ++cc8) {       // (c0,c1,c2), c2 fastest = product order
        int c0 = (cc8 >> 2) & 1, c1 = (cc8 >> 1) & 1, c2 = cc8 & 1;
        int j = (c0 ^ 1) * 4 + (yy + 1 - c1);
        int cz = z - c2;                      // in [0,79]
        unsigned e0 = cz ? sEndsRel[j][cz - 1] : 0u;
        unsigned e1 = sEndsRel[j][cz];
        unsigned ldsB = sColBase[j], glB = sLo[j];
        for (unsigned k = e0; k < e1; ++k) {
            uint4 e = useLds ? sEnt[ldsB + k] : entG[glB + k];
            unsigned key = e.x;
            float p0 = __uint_as_float(e.y);
            float p1 = __uint_as_float(e.z);
            float p2 = __uint_as_float(e.w);
            float w0 = 1.0f - fabsf(p0 - xf);
            float w1 = 1.0f - fabsf(p1 - yf);
            float w2 = 1.0f - fabsf(p2 - zf);
            float wt = nofuse_f((w0 * w1) * w2);   // ref assoc; no fma into add
            s0 += wt;
            if (win) {
                unsigned m = key & 0xFFFu;
#pragma unroll
                for (int c = 0; c < kNSEM; ++c)
                    if (m & (1u << c)) ssem[c] += wt;
            }
        }
    }

    float* col = (float*)(base + A_COL);
    int ij = y * kVR + x;
    float v0 = rintf(s0);                      // round half-to-even (f32)
    if (v0 != 0.0f) {
        atomicAdd(col + 1 * 10000 + ij, v0);            // exp (all z)
        if (win) atomicAdd(col + 0 * 10000 + ij, v0);   // map (window)
    }
    if (win) {
#pragma unroll
        for (int c = 0; c < kNSEM; ++c) {
            float vc = rintf(ssem[c]);
            if (vc != 0.0f) atomicAdd(col + (2 + c) * 10000 + ij, vc);
        }
    }
}

// K4 (direct, for 8/4-byte fallback layouts) — R13/R12-proven path.
template <int ESZ>
__global__ __launch_bounds__(256) void gather_kernel(
        const float* __restrict__ obs, char* __restrict__ ws,
        int b0, int nb, size_t entOff, float rcpF) {
    const int perb = 99 * 99 * 79;            // 774279
    int t = blockIdx.x * blockDim.x + threadIdx.x;
    if (t >= nb * perb) return;
    int lb = t / perb, r = t - lb * perb;
    int x = r / (99 * 79) + 1;
    int rem = r - (x - 1) * (99 * 79);
    int y = rem / 79 + 1;
    int z = rem - (y - 1) * 79 + 1;

    char* base = ws + (size_t)lb * A_STRIDE;
    const unsigned* cnt = (const unsigned*)(base + A_CNT);
    const char* entBase = ws + entOff + (size_t)lb * ((size_t)kNPIX * ESZ);
    const float* ob = obs + (size_t)(b0 + lb) * kNCH * kNPIX;

    bool win = (z >= kZLO) && (z < kZHI);
    float xf = (float)x, yf = (float)y, zf = (float)z;

    float s0 = 0.0f;
    float ssem[kNSEM];
#pragma unroll
    for (int c = 0; c < kNSEM; ++c) ssem[c] = 0.0f;

#pragma unroll
    for (int cc = 0; cc < 8; ++cc) {
        int c0 = (cc >> 2) & 1, c1 = (cc >> 1) & 1, c2 = cc & 1;
        unsigned cell = ((unsigned)((x - c0) * kVR + (y - c1))) * (unsigned)kNZ
                      + (unsigned)(z - c2);
        unsigned lo = (cell == 0u) ? 0u : cnt[cell - 1];
        unsigned hi = cnt[cell];
        for (unsigned k = lo; k < hi; ++k) {
            unsigned key; float p0, p1, p2;
            if constexpr (ESZ == 8) {
                uint2 e = ((const uint2*)entBase)[k];
                key = e.x;
                float d = __uint_as_float(e.y);
                int pix = (int)(key >> 12);
                int zi = pix / kW, xi = pix - zi * kW;
                geom_f(xi, zi, d, rcpF, p0, p1, p2);
            } else {
                key = ((const unsigned*)entBase)[k];
                int pix = (int)(key >> 12);
                int zi = pix / kW, xi = pix - zi * kW;
                float d = ob[3 * kNPIX + pix];
                geom_f(xi, zi, d, rcpF, p0, p1, p2);
            }
            float w0 = 1.0f - fabsf(p0 - xf);
            float w1 = 1.0f - fabsf(p1 - yf);
            float w2 = 1.0f - fabsf(p2 - zf);
            float wt = nofuse_f((w0 * w1) * w2);
            s0 += wt;
            if (win) {
                unsigned m = key & 0xFFFu;
#pragma unroll
                for (int c = 0; c < kNSEM; ++c)
                    if (m & (1u << c)) ssem[c] += wt;
            }
        }
    }

    float* col = (float*)(base + A_COL);
    int ij = y * kVR + x;
    float v0 = rintf(s0);
    if (v0 != 0.0f) {
        atomicAdd(col + 1 * 10000 + ij, v0);
        if (win) atomicAdd(col + 0 * 10000 + ij, v0);
    }
    if (win) {
#pragma unroll
        for (int c = 0; c < kNSEM; ++c) {
            float vc = rintf(ssem[c]);
            if (vc != 0.0f) atomicAdd(col + (2 + c) * 10000 + ij, vc);
        }
    }
}

// K5: clip column sums into output. /5 -> *0.2f (frozen).
__global__ __launch_bounds__(256) void finalize_kernel(
        const char* __restrict__ ws, float* __restrict__ out, int b0, int nb) {
    int t = blockIdx.x * blockDim.x + threadIdx.x;
    if (t >= nb * 14 * 10000) return;
    int lb = t / 140000, r = t - lb * 140000;
    int m = r / 10000, ij = r - m * 10000;
    int b = b0 + lb;
    const float* col = (const float*)(ws + (size_t)lb * A_STRIDE + A_COL);
    float v = col[m * 10000 + ij];
    if (m == 0)      out[b * 10000 + ij]              = fminf(fmaxf(v, 0.0f), 1.0f);
    else if (m == 1) out[kB * 10000 + b * 10000 + ij] = fminf(fmaxf(v, 0.0f), 1.0f);
    else             out[2 * kB * 10000 + (b * kNSEM + (m - 2)) * 10000 + ij]
                        = fminf(fmaxf(v * 0.2f, 0.0f), 1.0f);
}

// ---------------- host ----------------
template <int ESZ>
static void run_exact(const float* obs, float* out, char* ws,
                      int b0, int nb, float rcpF, hipStream_t stream) {
    size_t entOff = (size_t)nb * A_STRIDE;   // entries follow the A regions
    hipMemsetAsync(ws, 0, entOff, stream);   // ONE memset zeroes all cnt/part/col
    int n1 = nb * kNPIX;
    build_kernel<<<(n1 + 255) / 256, 256, 0, stream>>>(obs, ws, b0, nb, rcpF);
    scan_block_kernel<<<nb * kNCHUNK, 256, 0, stream>>>(ws);
    scan_partials_kernel<<<nb, 256, 0, stream>>>(ws);
    scan_add_kernel<<<nb * kNCHUNK, 256, 0, stream>>>(ws);
    scatter_kernel<ESZ><<<(n1 + 255) / 256, 256, 0, stream>>>(obs, ws, b0, nb, entOff, rcpF);
    int n2 = nb * kNCELL;
    sort_kernel<ESZ><<<(n2 + 255) / 256, 256, 0, stream>>>(ws, nb, entOff);
    if constexpr (ESZ == 16) {
        gather_lds_kernel<<<nb * 99 * 33, 256, 0, stream>>>(ws, nb, entOff);
    } else {
        int n3 = nb * 99 * 99 * 79;
        gather_kernel<ESZ><<<(n3 + 255) / 256, 256, 0, stream>>>(obs, ws, b0, nb, entOff, rcpF);
    }
    int n4 = nb * 14 * 10000;
    finalize_kernel<<<(n4 + 255) / 256, 256, 0, stream>>>(ws, out, b0, nb);
}

extern "C" void kernel_launch(void* const* d_in, const int* in_sizes, int n_in,
                              void* d_out, int out_size, void* d_ws, size_t ws_size,
                              hipStream_t stream) {
    const float* obs = (const float*)d_in[0];
    float* out = (float*)d_out;
    char* ws = (char*)d_ws;

    // F_CAM in f64 as numpy (deg2rad(x) = x*(pi/180)), demoted to the f32
    // graph literal; reciprocal folded in f32 (frozen, bit-exact R12-R14).
    double rad = (79.0 / 2.0) * (M_PI / 180.0);
    float f_cam = (float)(640.0 / 2.0 / tan(rad));
    float rcpF  = 1.0f / f_cam;

    auto need = [](int nb, int esz) {
        return (size_t)nb * A_STRIDE + (size_t)nb * (size_t)kNPIX * esz;
    };

    if (ws_size >= need(4, 16)) {            // 34.8 MB: parallel, LDS-staged gather
        run_exact<16>(obs, out, ws, 0, kB, rcpF, stream);
    } else if (ws_size >= need(4, 8)) {      // 24.9 MB: parallel, depth-in-entry (R13)
        run_exact<8>(obs, out, ws, 0, kB, rcpF, stream);
    } else if (ws_size >= need(1, 16)) {     // 8.7 MB: sequential, LDS-staged
        for (int b = 0; b < kB; ++b) run_exact<16>(obs, out, ws, b, 1, rcpF, stream);
    } else if (ws_size >= need(1, 8)) {      // 6.2 MB: sequential, depth-in-entry
        for (int b = 0; b < kB; ++b) run_exact<8>(obs, out, ws, b, 1, rcpF, stream);
    } else {                                 // 5.0 MB: sequential, key-only (R12)
        for (int b = 0; b < kB; ++b) run_exact<4>(obs, out, ws, b, 1, rcpF, stream);
    }
}

// Round 16
// 409.596 us; speedup vs baseline: 1.0118x; 1.0118x over previous
//
#include <hip/hip_runtime.h>
#include <math.h>

// Problem constants
constexpr int kB    = 4;
constexpr int kNSEM = 12;
constexpr int kH    = 480;
constexpr int kW    = 640;
constexpr int kNPIX = kH * kW;           // 307200
constexpr int kNCH  = 16;                // rgb(3) + depth(1) + sem(12)
constexpr int kVR   = 100;
constexpr int kNZ   = 80;
constexpr int kZLO  = 13;                // agent window [13,25)
constexpr int kZHI  = 25;
constexpr int kNCELL  = kVR * kVR * kNZ; // 800000 floor-cells
constexpr int kNCHUNK = kNCELL / 256;    // 3125

// ---- ws layout ----
// Region A (zeroed by ONE memset, per-batch stride A_STRIDE):
//   CNT (800000 u32) | PART (3136 u32) | COL (14x10000 f32)
// Region B (entries, per-batch stride kNPIX*ESZ), starts at entOff.
constexpr size_t A_CNT    = 0;
constexpr size_t A_PART   = (size_t)kNCELL * 4;          // 3,200,000
constexpr size_t A_COL    = A_PART + 12544;              // 3,212,544
constexpr size_t A_STRIDE = A_COL + (size_t)14 * 10000 * 4;  // 3,772,544

// Block hipcc contraction of the weight product into the accumulate add
// (XLA's scatter adds are separately rounded).
__device__ __forceinline__ float nofuse_f(float x) {
    asm volatile("" : "+v"(x));
    return x;
}

// XLA-jit canonical geometry — FROZEN (bit-exact vs golden, R12-R15):
//   p0 = fma(tx, rcpF, 250) * 0.2f
//   p1 = d * 0.2f
//   p2 = fma(fma(tz, rcpF, 88), 0.2f, 8)
__device__ __forceinline__ void geom_f(int xi, int zi, float d, float rcpF,
                                       float& p0, float& p1, float& p2) {
    float tx  = ((float)xi - 319.5f) * d;
    float tz  = (239.5f - (float)zi) * d;
    float x_w = fmaf(tx, rcpF, 250.0f);
    float z_w = fmaf(tz, rcpF, 88.0f);
    p0 = x_w * 0.2f;
    p1 = d   * 0.2f;
    p2 = fmaf(z_w, 0.2f, 8.0f);
}

// mask policy: sem bits are only consumed by win-voxels (z in [13,25)),
// which gather only buckets fz in [12,24]. For other entries mask:=0
// (never read) — skips 12 sem loads for ~84% of pixels.
__device__ __forceinline__ bool cellmask(const float* __restrict__ ob, int pix,
                                         float rcpF, unsigned& cell, unsigned& mask,
                                         float& d, float& p0, float& p1, float& p2,
                                         bool want_mask) {
    int zi = pix / kW, xi = pix - zi * kW;
    d = ob[3 * kNPIX + pix];
    geom_f(xi, zi, d, rcpF, p0, p1, p2);
    int fx = (int)floorf(p0), fy = (int)floorf(p1), fz = (int)floorf(p2);
    if (fx < 0 || fx >= kVR || fy < 0 || fy >= kVR || fz < 0 || fz >= kNZ)
        return false;
    cell = ((unsigned)(fx * kVR + fy)) * (unsigned)kNZ + (unsigned)fz;
    mask = 0;
    if (want_mask && fz >= (kZLO - 1) && fz < kZHI) {   // fz in [12,24]
#pragma unroll
        for (int c = 0; c < kNSEM; ++c)
            if (ob[(4 + c) * kNPIX + pix] != 0.0f) mask |= (1u << c);
    }
    return true;
}

// K1: count pixels per floor cell.
__global__ __launch_bounds__(256) void build_kernel(
        const float* __restrict__ obs, char* __restrict__ ws,
        int b0, int nb, float rcpF) {
    int t = blockIdx.x * blockDim.x + threadIdx.x;
    if (t >= nb * kNPIX) return;
    int lb = t / kNPIX, pix = t - lb * kNPIX;
    const float* ob = obs + (size_t)(b0 + lb) * kNCH * kNPIX;
    unsigned cell, mask; float d, p0, p1, p2;
    if (cellmask(ob, pix, rcpF, cell, mask, d, p0, p1, p2, false))
        atomicAdd((unsigned*)(ws + (size_t)lb * A_STRIDE + A_CNT) + cell, 1u);
}

// K2a: per 256-cell chunk — in-place chunk-exclusive scan; chunk total -> part.
__global__ __launch_bounds__(256) void scan_block_kernel(char* __restrict__ ws) {
    int blk = blockIdx.x, t = threadIdx.x;
    int lb = blk / kNCHUNK, chunk = blk - lb * kNCHUNK;
    char* base = ws + (size_t)lb * A_STRIDE;
    unsigned* cnt  = (unsigned*)(base + A_CNT);
    unsigned* part = (unsigned*)(base + A_PART);
    int i = chunk * 256 + t;
    unsigned v = cnt[i];
    __shared__ unsigned s[256];
    s[t] = v; __syncthreads();
#pragma unroll
    for (int dd = 1; dd < 256; dd <<= 1) {
        unsigned x = (t >= dd) ? s[t - dd] : 0u;
        __syncthreads();
        s[t] += x;
        __syncthreads();
    }
    cnt[i] = s[t] - v;
    if (t == 255) part[chunk] = s[255];
}

// K2b: one block per batch — in-place exclusive scan of the 3125 partials.
__global__ __launch_bounds__(256) void scan_partials_kernel(char* __restrict__ ws) {
    int lb = blockIdx.x, t = threadIdx.x;
    unsigned* p = (unsigned*)(ws + (size_t)lb * A_STRIDE + A_PART);
    const int per = (kNCHUNK + 255) / 256;    // 13
    int lo = t * per, hi = lo + per; if (hi > kNCHUNK) hi = kNCHUNK;
    unsigned sum = 0;
    for (int i = lo; i < hi; ++i) sum += p[i];
    __shared__ unsigned s[256];
    s[t] = sum; __syncthreads();
    unsigned own = sum;
#pragma unroll
    for (int dd = 1; dd < 256; dd <<= 1) {
        unsigned x = (t >= dd) ? s[t - dd] : 0u;
        __syncthreads();
        s[t] += x;
        __syncthreads();
    }
    unsigned running = s[t] - own;
    for (int i = lo; i < hi; ++i) {
        unsigned tmp = p[i]; p[i] = running; running += tmp;
    }
}

// K2c: cnt[i] += chunk base -> global exclusive offsets (= scatter cursor).
__global__ __launch_bounds__(256) void scan_add_kernel(char* __restrict__ ws) {
    int blk = blockIdx.x, t = threadIdx.x;
    int lb = blk / kNCHUNK, chunk = blk - lb * kNCHUNK;
    char* base = ws + (size_t)lb * A_STRIDE;
    unsigned* cnt = (unsigned*)(base + A_CNT);
    const unsigned* part = (const unsigned*)(base + A_PART);
    cnt[chunk * 256 + t] += part[chunk];
}

// K3: scatter entries into buckets. After: cnt[c] == END of bucket c.
template <int ESZ>
__global__ __launch_bounds__(256) void scatter_kernel(
        const float* __restrict__ obs, char* __restrict__ ws,
        int b0, int nb, size_t entOff, float rcpF) {
    int t = blockIdx.x * blockDim.x + threadIdx.x;
    if (t >= nb * kNPIX) return;
    int lb = t / kNPIX, pix = t - lb * kNPIX;
    const float* ob = obs + (size_t)(b0 + lb) * kNCH * kNPIX;
    unsigned cell, mask; float d, p0, p1, p2;
    if (!cellmask(ob, pix, rcpF, cell, mask, d, p0, p1, p2, true)) return;
    unsigned slot = atomicAdd(
        (unsigned*)(ws + (size_t)lb * A_STRIDE + A_CNT) + cell, 1u);
    unsigned key = ((unsigned)pix << 12) | mask;
    char* entBase = ws + entOff + (size_t)lb * ((size_t)kNPIX * ESZ);
    if constexpr (ESZ == 16) {
        uint4 e; e.x = key; e.y = __float_as_uint(p0);
        e.z = __float_as_uint(p1); e.w = __float_as_uint(p2);
        ((uint4*)entBase)[slot] = e;
    } else if constexpr (ESZ == 8) {
        uint2 e; e.x = key; e.y = __float_as_uint(d);
        ((uint2*)entBase)[slot] = e;
    } else {
        ((unsigned*)entBase)[slot] = key;
    }
}

// K3s: per cell — insertion-sort its bucket ascending by key (= pix order).
template <int ESZ>
__global__ __launch_bounds__(256) void sort_kernel(
        char* __restrict__ ws, int nb, size_t entOff) {
    int t = blockIdx.x * blockDim.x + threadIdx.x;
    if (t >= nb * kNCELL) return;
    int lb = t / kNCELL, c = t - lb * kNCELL;
    const unsigned* cnt = (const unsigned*)(ws + (size_t)lb * A_STRIDE + A_CNT);
    int lo = (c == 0) ? 0 : (int)cnt[c - 1];
    int hi = (int)cnt[c];
    char* entBase = ws + entOff + (size_t)lb * ((size_t)kNPIX * ESZ);
    if constexpr (ESZ == 16) {
        uint4* ent = (uint4*)entBase;
        for (int i = lo + 1; i < hi; ++i) {
            uint4 v = ent[i]; int j = i - 1;
            while (j >= lo && ent[j].x > v.x) { ent[j + 1] = ent[j]; --j; }
            ent[j + 1] = v;
        }
    } else if constexpr (ESZ == 8) {
        uint2* ent = (uint2*)entBase;
        for (int i = lo + 1; i < hi; ++i) {
            uint2 v = ent[i]; int j = i - 1;
            while (j >= lo && ent[j].x > v.x) { ent[j + 1] = ent[j]; --j; }
            ent[j + 1] = v;
        }
    } else {
        unsigned* ent = (unsigned*)entBase;
        for (int i = lo + 1; i < hi; ++i) {
            unsigned v = ent[i]; int j = i - 1;
            while (j >= lo && ent[j] > v) { ent[j + 1] = ent[j]; --j; }
            ent[j + 1] = v;
        }
    }
}

// K4 (LDS-staged, ESZ=16): block = (x0, y0..y0+2, all z). Stages the 8
// needed cell-columns' contiguous entry ranges + bucket ends into LDS; the
// per-voxel scan order and arithmetic are bit-identical to the proven path.
// Uniform fallback to global reads (sorted) if the ranges exceed CAP.
// CAP=1792: 28KB entries + 2.5KB ends -> ~31.4KB/block -> 5 blocks/CU.
// Worst-case block load (count/col ~ 2044/fy, worst cy-set {10..13}) ~1120.
constexpr int kCAP = 1792;
__global__ __launch_bounds__(256) void gather_lds_kernel(
        char* __restrict__ ws, int nb, size_t entOff) {
    __shared__ uint4    sEnt[kCAP];
    __shared__ unsigned sEndsRel[8][80];
    __shared__ unsigned sCellcol[8], sLo[8], sLen[8], sColBase[8];
    __shared__ unsigned sTotal;

    const int per = 99 * 33;
    int bid = blockIdx.x;
    int lb = bid / per, r = bid - lb * per;
    int x0 = r / 33 + 1;
    int yt = r - (r / 33) * 33;
    int y0 = yt * 3 + 1;

    char* base = ws + (size_t)lb * A_STRIDE;
    const unsigned* cnt = (const unsigned*)(base + A_CNT);
    const uint4* entG = (const uint4*)(ws + entOff + (size_t)lb * ((size_t)kNPIX * 16));

    int t = threadIdx.x;
    if (t < 8) {
        int jx = t >> 2, jy = t & 3;
        int cx = x0 - 1 + jx, cy = y0 - 1 + jy;
        unsigned cc = ((unsigned)(cx * kVR + cy)) * (unsigned)kNZ;
        unsigned lo = (cc == 0u) ? 0u : cnt[cc - 1];
        unsigned hi = cnt[cc + (kNZ - 1)];
        sCellcol[t] = cc; sLo[t] = lo; sLen[t] = hi - lo;
    }
    __syncthreads();
    if (t == 0) {
        unsigned b = 0;
        for (int j = 0; j < 8; ++j) { sColBase[j] = b; b += sLen[j]; }
        sTotal = b;
    }
    __syncthreads();
    for (int i = t; i < 8 * kNZ; i += 256) {
        int j = i / kNZ, cz = i - j * kNZ;
        sEndsRel[j][cz] = cnt[sCellcol[j] + cz] - sLo[j];
    }
    unsigned total = sTotal;
    bool useLds = (total <= (unsigned)kCAP);
    if (useLds) {
        for (unsigned i = t; i < total; i += 256) {
            int j = 0;
            while (j < 7 && i >= sColBase[j + 1]) ++j;
            sEnt[i] = entG[sLo[j] + (i - sColBase[j])];
        }
    }
    __syncthreads();

    if (t >= 3 * 79) return;
    int yy = t / 79, zz = t - yy * 79;
    int x = x0, y = y0 + yy, z = zz + 1;

    bool win = (z >= kZLO) && (z < kZHI);
    float xf = (float)x, yf = (float)y, zf = (float)z;

    float s0 = 0.0f;
    float ssem[kNSEM];
#pragma unroll
    for (int c = 0; c < kNSEM; ++c) ssem[c] = 0.0f;

#pragma unroll
    for (int cc8 = 0; cc8 < 8; ++cc8) {       // (c0,c1,c2), c2 fastest = product order
        int c0 = (cc8 >> 2) & 1, c1 = (cc8 >> 1) & 1, c2 = cc8 & 1;
        int j = (c0 ^ 1) * 4 + (yy + 1 - c1);
        int cz = z - c2;                      // in [0,79]
        unsigned e0 = cz ? sEndsRel[j][cz - 1] : 0u;
        unsigned e1 = sEndsRel[j][cz];
        unsigned ldsB = sColBase[j], glB = sLo[j];
        for (unsigned k = e0; k < e1; ++k) {
            uint4 e = useLds ? sEnt[ldsB + k] : entG[glB + k];
            unsigned key = e.x;
            float p0 = __uint_as_float(e.y);
            float p1 = __uint_as_float(e.z);
            float p2 = __uint_as_float(e.w);
            float w0 = 1.0f - fabsf(p0 - xf);
            float w1 = 1.0f - fabsf(p1 - yf);
            float w2 = 1.0f - fabsf(p2 - zf);
            float wt = nofuse_f((w0 * w1) * w2);   // ref assoc; no fma into add
            s0 += wt;
            if (win) {
                unsigned m = key & 0xFFFu;
#pragma unroll
                for (int c = 0; c < kNSEM; ++c)
                    if (m & (1u << c)) ssem[c] += wt;
            }
        }
    }

    float* col = (float*)(base + A_COL);
    int ij = y * kVR + x;
    float v0 = rintf(s0);                      // round half-to-even (f32)
    if (v0 != 0.0f) {
        atomicAdd(col + 1 * 10000 + ij, v0);            // exp (all z)
        if (win) atomicAdd(col + 0 * 10000 + ij, v0);   // map (window)
    }
    if (win) {
#pragma unroll
        for (int c = 0; c < kNSEM; ++c) {
            float vc = rintf(ssem[c]);
            if (vc != 0.0f) atomicAdd(col + (2 + c) * 10000 + ij, vc);
        }
    }
}

// K4 (direct, for 8/4-byte fallback layouts) — R13/R12-proven path.
template <int ESZ>
__global__ __launch_bounds__(256) void gather_kernel(
        const float* __restrict__ obs, char* __restrict__ ws,
        int b0, int nb, size_t entOff, float rcpF) {
    const int perb = 99 * 99 * 79;            // 774279
    int t = blockIdx.x * blockDim.x + threadIdx.x;
    if (t >= nb * perb) return;
    int lb = t / perb, r = t - lb * perb;
    int x = r / (99 * 79) + 1;
    int rem = r - (x - 1) * (99 * 79);
    int y = rem / 79 + 1;
    int z = rem - (y - 1) * 79 + 1;

    char* base = ws + (size_t)lb * A_STRIDE;
    const unsigned* cnt = (const unsigned*)(base + A_CNT);
    const char* entBase = ws + entOff + (size_t)lb * ((size_t)kNPIX * ESZ);
    const float* ob = obs + (size_t)(b0 + lb) * kNCH * kNPIX;

    bool win = (z >= kZLO) && (z < kZHI);
    float xf = (float)x, yf = (float)y, zf = (float)z;

    float s0 = 0.0f;
    float ssem[kNSEM];
#pragma unroll
    for (int c = 0; c < kNSEM; ++c) ssem[c] = 0.0f;

#pragma unroll
    for (int cc = 0; cc < 8; ++cc) {
        int c0 = (cc >> 2) & 1, c1 = (cc >> 1) & 1, c2 = cc & 1;
        unsigned cell = ((unsigned)((x - c0) * kVR + (y - c1))) * (unsigned)kNZ
                      + (unsigned)(z - c2);
        unsigned lo = (cell == 0u) ? 0u : cnt[cell - 1];
        unsigned hi = cnt[cell];
        for (unsigned k = lo; k < hi; ++k) {
            unsigned key; float p0, p1, p2;
            if constexpr (ESZ == 8) {
                uint2 e = ((const uint2*)entBase)[k];
                key = e.x;
                float d = __uint_as_float(e.y);
                int pix = (int)(key >> 12);
                int zi = pix / kW, xi = pix - zi * kW;
                geom_f(xi, zi, d, rcpF, p0, p1, p2);
            } else {
                key = ((const unsigned*)entBase)[k];
                int pix = (int)(key >> 12);
                int zi = pix / kW, xi = pix - zi * kW;
                float d = ob[3 * kNPIX + pix];
                geom_f(xi, zi, d, rcpF, p0, p1, p2);
            }
            float w0 = 1.0f - fabsf(p0 - xf);
            float w1 = 1.0f - fabsf(p1 - yf);
            float w2 = 1.0f - fabsf(p2 - zf);
            float wt = nofuse_f((w0 * w1) * w2);
            s0 += wt;
            if (win) {
                unsigned m = key & 0xFFFu;
#pragma unroll
                for (int c = 0; c < kNSEM; ++c)
                    if (m & (1u << c)) ssem[c] += wt;
            }
        }
    }

    float* col = (float*)(base + A_COL);
    int ij = y * kVR + x;
    float v0 = rintf(s0);
    if (v0 != 0.0f) {
        atomicAdd(col + 1 * 10000 + ij, v0);
        if (win) atomicAdd(col + 0 * 10000 + ij, v0);
    }
    if (win) {
#pragma unroll
        for (int c = 0; c < kNSEM; ++c) {
            float vc = rintf(ssem[c]);
            if (vc != 0.0f) atomicAdd(col + (2 + c) * 10000 + ij, vc);
        }
    }
}

// K5: clip column sums into output. /5 -> *0.2f (frozen).
__global__ __launch_bounds__(256) void finalize_kernel(
        const char* __restrict__ ws, float* __restrict__ out, int b0, int nb) {
    int t = blockIdx.x * blockDim.x + threadIdx.x;
    if (t >= nb * 14 * 10000) return;
    int lb = t / 140000, r = t - lb * 140000;
    int m = r / 10000, ij = r - m * 10000;
    int b = b0 + lb;
    const float* col = (const float*)(ws + (size_t)lb * A_STRIDE + A_COL);
    float v = col[m * 10000 + ij];
    if (m == 0)      out[b * 10000 + ij]              = fminf(fmaxf(v, 0.0f), 1.0f);
    else if (m == 1) out[kB * 10000 + b * 10000 + ij] = fminf(fmaxf(v, 0.0f), 1.0f);
    else             out[2 * kB * 10000 + (b * kNSEM + (m - 2)) * 10000 + ij]
                        = fminf(fmaxf(v * 0.2f, 0.0f), 1.0f);
}

// ---------------- host ----------------
template <int ESZ>
static void run_exact(const float* obs, float* out, char* ws,
                      int b0, int nb, float rcpF, hipStream_t stream) {
    size_t entOff = (size_t)nb * A_STRIDE;   // entries follow the A regions
    hipMemsetAsync(ws, 0, entOff, stream);   // ONE memset zeroes all cnt/part/col
    int n1 = nb * kNPIX;
    build_kernel<<<(n1 + 255) / 256, 256, 0, stream>>>(obs, ws, b0, nb, rcpF);
    scan_block_kernel<<<nb * kNCHUNK, 256, 0, stream>>>(ws);
    scan_partials_kernel<<<nb, 256, 0, stream>>>(ws);
    scan_add_kernel<<<nb * kNCHUNK, 256, 0, stream>>>(ws);
    scatter_kernel<ESZ><<<(n1 + 255) / 256, 256, 0, stream>>>(obs, ws, b0, nb, entOff, rcpF);
    int n2 = nb * kNCELL;
    sort_kernel<ESZ><<<(n2 + 255) / 256, 256, 0, stream>>>(ws, nb, entOff);
    if constexpr (ESZ == 16) {
        gather_lds_kernel<<<nb * 99 * 33, 256, 0, stream>>>(ws, nb, entOff);
    } else {
        int n3 = nb * 99 * 99 * 79;
        gather_kernel<ESZ><<<(n3 + 255) / 256, 256, 0, stream>>>(obs, ws, b0, nb, entOff, rcpF);
    }
    int n4 = nb * 14 * 10000;
    finalize_kernel<<<(n4 + 255) / 256, 256, 0, stream>>>(ws, out, b0, nb);
}

extern "C" void kernel_launch(void* const* d_in, const int* in_sizes, int n_in,
                              void* d_out, int out_size, void* d_ws, size_t ws_size,
                              hipStream_t stream) {
    const float* obs = (const float*)d_in[0];
    float* out = (float*)d_out;
    char* ws = (char*)d_ws;

    // F_CAM in f64 as numpy (deg2rad(x) = x*(pi/180)), demoted to the f32
    // graph literal; reciprocal folded in f32 (frozen, bit-exact R12-R15).
    double rad = (79.0 / 2.0) * (M_PI / 180.0);
    float f_cam = (float)(640.0 / 2.0 / tan(rad));
    float rcpF  = 1.0f / f_cam;

    auto need = [](int nb, int esz) {
        return (size_t)nb * A_STRIDE + (size_t)nb * (size_t)kNPIX * esz;
    };

    if (ws_size >= need(4, 16)) {            // 34.8 MB: parallel, LDS-staged gather
        run_exact<16>(obs, out, ws, 0, kB, rcpF, stream);
    } else if (ws_size >= need(4, 8)) {      // 24.9 MB: parallel, depth-in-entry (R13)
        run_exact<8>(obs, out, ws, 0, kB, rcpF, stream);
    } else if (ws_size >= need(1, 16)) {     // 8.7 MB: sequential, LDS-staged
        for (int b = 0; b < kB; ++b) run_exact<16>(obs, out, ws, b, 1, rcpF, stream);
    } else if (ws_size >= need(1, 8)) {      // 6.2 MB: sequential, depth-in-entry
        for (int b = 0; b < kB; ++b) run_exact<8>(obs, out, ws, b, 1, rcpF, stream);
    } else {                                 // 5.0 MB: sequential, key-only (R12)
        for (int b = 0; b < kB; ++b) run_exact<4>(obs, out, ws, b, 1, rcpF, stream);
    }
}